// Round 1
// baseline (251.415 us; speedup 1.0000x reference)
//
#include <hip/hip_runtime.h>
#include <hip/hip_bf16.h>
#include <stdint.h>

#define E_   16
#define T_   512
#define KTOP 8
#define H_   2048
#define I_   1024
#define TK_  4096

typedef __attribute__((ext_vector_type(8))) short bf16x8;
typedef __attribute__((ext_vector_type(4))) float f32x4;

// ---- ws layout (bytes) ----
#define OFF_CNT     0                         // u32[16] expert counts/cursors
#define OFF_ROWMAX  4096                      // u32[4096] abs-max bits per row
#define OFF_XQ      32768                     // bf16 [512][2048]
#define OFF_S0      (OFF_XQ + T_*H_*2)        // f32 [512]
#define OFF_S1      (OFF_S0 + 2048)           // f32 [4096]
#define OFF_LIST    (OFF_S1 + TK_*4)          // i32 [16][4096]
#define OFF_ACT     (OFF_LIST + E_*TK_*4)     // f32 [4096][1024]
#define OFF_AQ      (OFF_ACT + (size_t)TK_*I_*4)   // bf16 [4096][1024]
#define OFF_Y2      (OFF_AQ + (size_t)TK_*I_*2)    // f32 [4096][2048]

__device__ __forceinline__ unsigned short f2bf(float f) {
  // exact for small integers (|v| <= 256): low 16 mantissa bits are zero
  return (unsigned short)(__float_as_uint(f) >> 16);
}

// ---------------- dynamic quant of x ----------------
__global__ void k_quant(const float* __restrict__ x, unsigned short* __restrict__ xq,
                        float* __restrict__ s0) {
  int t = blockIdx.x;
  int tid = threadIdx.x;
  const float4* xr = (const float4*)(x + (size_t)t * H_);
  float4 a = xr[tid * 2 + 0], b = xr[tid * 2 + 1];
  float m = fmaxf(
      fmaxf(fmaxf(fabsf(a.x), fabsf(a.y)), fmaxf(fabsf(a.z), fabsf(a.w))),
      fmaxf(fmaxf(fabsf(b.x), fabsf(b.y)), fmaxf(fabsf(b.z), fabsf(b.w))));
  for (int o = 32; o > 0; o >>= 1) m = fmaxf(m, __shfl_xor(m, o));
  __shared__ float wm[4];
  if ((tid & 63) == 0) wm[tid >> 6] = m;
  __syncthreads();
  m = fmaxf(fmaxf(wm[0], wm[1]), fmaxf(wm[2], wm[3]));
  float s = m / 127.0f;
  if (!(s > 0.f)) s = 1.0f;
  if (tid == 0) s0[t] = s;
  float v[8] = {a.x, a.y, a.z, a.w, b.x, b.y, b.z, b.w};
  unsigned short q[8];
#pragma unroll
  for (int j = 0; j < 8; ++j) {
    float qf = rintf(v[j] / s);
    qf = fminf(fmaxf(qf, -128.f), 127.f);
    q[j] = f2bf(qf);
  }
  ushort4* dst = (ushort4*)(xq + (size_t)t * H_ + tid * 8);
  dst[0] = make_ushort4(q[0], q[1], q[2], q[3]);
  dst[1] = make_ushort4(q[4], q[5], q[6], q[7]);
}

// ---------------- expert dispatch (scatter) ----------------
__global__ void k_scatter(const int* __restrict__ eids, unsigned int* __restrict__ counts,
                          int* __restrict__ row_list) {
  int i = blockIdx.x * blockDim.x + threadIdx.x;   // 0..4095
  int e = eids[i];
  int pos = (int)atomicAdd(&counts[e], 1u);
  row_list[e * TK_ + pos] = i;
}

// ---------------- grouped GEMM1 + SwiGLU + rowmax ----------------
#define BM_   384
#define BK_   32
#define LDSP_ 40   // padded LDS row length (ushorts)

__launch_bounds__(512)
__global__ void k_gemm1(const unsigned short* __restrict__ xq, const int* __restrict__ w1,
                        const float* __restrict__ ws1, const float* __restrict__ s0,
                        const unsigned int* __restrict__ counts, const int* __restrict__ row_list,
                        float* __restrict__ act, unsigned int* __restrict__ rowmax) {
  int e = blockIdx.y;
  int cnt = (int)counts[e];
  if (cnt == 0) return;
  int p0 = blockIdx.x * 64;                       // pair (left-col) offset
  const int* rl = row_list + e * TK_;
  const int* we = w1 + (size_t)e * H_ * (2 * I_);
  const float* wsc = ws1 + (size_t)e * (2 * I_);

  __shared__ unsigned short As[BM_ * LDSP_];
  __shared__ unsigned short Bs[128 * LDSP_];

  int tid = threadIdx.x;
  int wid = tid >> 6, lane = tid & 63;
  int l15 = lane & 15, l4 = lane >> 4;

  // B staging decode: logical col c pairs (left,right) interleaved
  int bc = tid & 127, bkk = tid >> 7;
  int bpair = bc >> 1, bside = bc & 1;
  int bgcol = bside ? (I_ + p0 + bpair) : (p0 + bpair);
  // A staging decode
  int ar = tid >> 2, akk = (tid & 3) * 8;

  int nchunks = (cnt + BM_ - 1) / BM_;
  for (int ch = 0; ch < nchunks; ++ch) {
    int rbase = ch * BM_;
    f32x4 acc[3][8];
#pragma unroll
    for (int mi = 0; mi < 3; ++mi)
#pragma unroll
      for (int ni = 0; ni < 8; ++ni) acc[mi][ni] = (f32x4)(0.f);

    int tok[3];
#pragma unroll
    for (int sl = 0; sl < 3; ++sl) {
      int gr = rbase + sl * 128 + ar;
      tok[sl] = rl[gr < cnt ? gr : 0] >> 3;       // token index = i / K
    }

    for (int k0 = 0; k0 < H_; k0 += BK_) {
      __syncthreads();
#pragma unroll
      for (int sl = 0; sl < 3; ++sl) {
        const uint4* src = (const uint4*)(xq + (size_t)tok[sl] * H_ + k0 + akk);
        *(uint4*)(&As[(sl * 128 + ar) * LDSP_ + akk]) = *src;
      }
      {
        const int* src = we + (size_t)(k0 + bkk * 8) * (2 * I_) + bgcol;
        unsigned short tq[8];
#pragma unroll
        for (int j = 0; j < 8; ++j) tq[j] = f2bf((float)src[(size_t)j * (2 * I_)]);
        uint4 pk;
        pk.x = (unsigned)tq[0] | ((unsigned)tq[1] << 16);
        pk.y = (unsigned)tq[2] | ((unsigned)tq[3] << 16);
        pk.z = (unsigned)tq[4] | ((unsigned)tq[5] << 16);
        pk.w = (unsigned)tq[6] | ((unsigned)tq[7] << 16);
        *(uint4*)(&Bs[bc * LDSP_ + bkk * 8]) = pk;
      }
      __syncthreads();
      bf16x8 a[3];
#pragma unroll
      for (int mi = 0; mi < 3; ++mi)
        a[mi] = *(const bf16x8*)(&As[(wid * 48 + mi * 16 + l15) * LDSP_ + l4 * 8]);
#pragma unroll
      for (int ni = 0; ni < 8; ++ni) {
        bf16x8 b = *(const bf16x8*)(&Bs[(ni * 16 + l15) * LDSP_ + l4 * 8]);
#pragma unroll
        for (int mi = 0; mi < 3; ++mi)
          acc[mi][ni] = __builtin_amdgcn_mfma_f32_16x16x32_bf16(a[mi], b, acc[mi][ni], 0, 0, 0);
      }
    }

    // epilogue: dequant, SwiGLU via lane-pair shuffle, act store + rowmax
#pragma unroll
    for (int mi = 0; mi < 3; ++mi) {
#pragma unroll
      for (int r = 0; r < 4; ++r) {
        int gr = rbase + wid * 48 + mi * 16 + l4 * 4 + r;
        bool valid = gr < cnt;
        int i = rl[valid ? gr : 0];
        float s0v = s0[i >> 3];
        float rowm = 0.f;
#pragma unroll
        for (int ni = 0; ni < 8; ++ni) {
          int c = ni * 16 + l15;
          int pair = c >> 1;
          int gcol = (c & 1) ? (I_ + p0 + pair) : (p0 + pair);
          float y = (acc[mi][ni][r] * wsc[gcol]) * s0v;
          float other = __shfl_xor(y, 1);
          float actv = (y / (1.f + expf(-y))) * other;   // meaningful on even lanes
          float am = ((l15 & 1) == 0) ? fabsf(actv) : 0.f;
          rowm = fmaxf(rowm, am);
          if (valid && ((l15 & 1) == 0))
            act[(size_t)i * I_ + p0 + pair] = actv;
        }
        rowm = fmaxf(rowm, __shfl_xor(rowm, 1));
        rowm = fmaxf(rowm, __shfl_xor(rowm, 2));
        rowm = fmaxf(rowm, __shfl_xor(rowm, 4));
        rowm = fmaxf(rowm, __shfl_xor(rowm, 8));
        if (valid && l15 == 0) atomicMax(rowmax + i, __float_as_uint(rowm));
      }
    }
  }
}

// ---------------- requant act -> aq bf16 + s1 ----------------
__global__ void k_requant(const float* __restrict__ act, const unsigned int* __restrict__ rowmax,
                          unsigned short* __restrict__ aq, float* __restrict__ s1) {
  int i = blockIdx.x;
  int tid = threadIdx.x;
  float m = __uint_as_float(rowmax[i]);
  float s = (m > 0.f) ? (m / 127.0f) : 1.0f;
  if (tid == 0) s1[i] = s;
  float4 v = ((const float4*)(act + (size_t)i * I_))[tid];
  float vv[4] = {v.x, v.y, v.z, v.w};
  unsigned short q[4];
#pragma unroll
  for (int j = 0; j < 4; ++j) {
    float qf = rintf(vv[j] / s);
    qf = fminf(fmaxf(qf, -128.f), 127.f);
    q[j] = f2bf(qf);
  }
  *(ushort4*)(aq + (size_t)i * I_ + tid * 4) = make_ushort4(q[0], q[1], q[2], q[3]);
}

// ---------------- grouped GEMM2 + dequant ----------------
__launch_bounds__(512)
__global__ void k_gemm2(const unsigned short* __restrict__ aq, const int* __restrict__ w2,
                        const float* __restrict__ ws2, const float* __restrict__ s1,
                        const unsigned int* __restrict__ counts, const int* __restrict__ row_list,
                        float* __restrict__ y2) {
  int e = blockIdx.y;
  int cnt = (int)counts[e];
  if (cnt == 0) return;
  int n0 = blockIdx.x * 128;
  const int* rl = row_list + e * TK_;
  const int* we = w2 + (size_t)e * I_ * H_;
  const float* wsc = ws2 + (size_t)e * H_;

  __shared__ unsigned short As[BM_ * LDSP_];
  __shared__ unsigned short Bs[128 * LDSP_];

  int tid = threadIdx.x;
  int wid = tid >> 6, lane = tid & 63;
  int l15 = lane & 15, l4 = lane >> 4;

  int bc = tid & 127, bkk = tid >> 7;
  int ar = tid >> 2, akk = (tid & 3) * 8;

  int nchunks = (cnt + BM_ - 1) / BM_;
  for (int ch = 0; ch < nchunks; ++ch) {
    int rbase = ch * BM_;
    f32x4 acc[3][8];
#pragma unroll
    for (int mi = 0; mi < 3; ++mi)
#pragma unroll
      for (int ni = 0; ni < 8; ++ni) acc[mi][ni] = (f32x4)(0.f);

    int row_i[3];
#pragma unroll
    for (int sl = 0; sl < 3; ++sl) {
      int gr = rbase + sl * 128 + ar;
      row_i[sl] = rl[gr < cnt ? gr : 0];
    }

    for (int k0 = 0; k0 < I_; k0 += BK_) {
      __syncthreads();
#pragma unroll
      for (int sl = 0; sl < 3; ++sl) {
        const uint4* src = (const uint4*)(aq + (size_t)row_i[sl] * I_ + k0 + akk);
        *(uint4*)(&As[(sl * 128 + ar) * LDSP_ + akk]) = *src;
      }
      {
        const int* src = we + (size_t)(k0 + bkk * 8) * H_ + n0 + bc;
        unsigned short tq[8];
#pragma unroll
        for (int j = 0; j < 8; ++j) tq[j] = f2bf((float)src[(size_t)j * H_]);
        uint4 pk;
        pk.x = (unsigned)tq[0] | ((unsigned)tq[1] << 16);
        pk.y = (unsigned)tq[2] | ((unsigned)tq[3] << 16);
        pk.z = (unsigned)tq[4] | ((unsigned)tq[5] << 16);
        pk.w = (unsigned)tq[6] | ((unsigned)tq[7] << 16);
        *(uint4*)(&Bs[bc * LDSP_ + bkk * 8]) = pk;
      }
      __syncthreads();
      bf16x8 a[3];
#pragma unroll
      for (int mi = 0; mi < 3; ++mi)
        a[mi] = *(const bf16x8*)(&As[(wid * 48 + mi * 16 + l15) * LDSP_ + l4 * 8]);
#pragma unroll
      for (int ni = 0; ni < 8; ++ni) {
        bf16x8 b = *(const bf16x8*)(&Bs[(ni * 16 + l15) * LDSP_ + l4 * 8]);
#pragma unroll
        for (int mi = 0; mi < 3; ++mi)
          acc[mi][ni] = __builtin_amdgcn_mfma_f32_16x16x32_bf16(a[mi], b, acc[mi][ni], 0, 0, 0);
      }
    }

#pragma unroll
    for (int mi = 0; mi < 3; ++mi) {
#pragma unroll
      for (int r = 0; r < 4; ++r) {
        int gr = rbase + wid * 48 + mi * 16 + l4 * 4 + r;
        if (gr < cnt) {
          int i = rl[gr];
          float s1v = s1[i];
#pragma unroll
          for (int ni = 0; ni < 8; ++ni) {
            int gcol = n0 + ni * 16 + l15;
            y2[(size_t)i * H_ + gcol] = (acc[mi][ni][r] * wsc[gcol]) * s1v;
          }
        }
      }
    }
  }
}

// ---------------- combine ----------------
__global__ void k_combine(const float* __restrict__ y2, const float* __restrict__ es,
                          float* __restrict__ out) {
  int idx = blockIdx.x * 256 + threadIdx.x;   // 0 .. T*H-1
  int t = idx >> 11, h = idx & (H_ - 1);
  const float* esr = es + (size_t)t * KTOP;
  float s = 0.f;
#pragma unroll
  for (int k = 0; k < KTOP; ++k)
    s += esr[k] * y2[(size_t)(t * KTOP + k) * H_ + h];
  out[idx] = s;
}

extern "C" void kernel_launch(void* const* d_in, const int* in_sizes, int n_in,
                              void* d_out, int out_size, void* d_ws, size_t ws_size,
                              hipStream_t stream) {
  const float* x   = (const float*)d_in[0];
  const int*   eid = (const int*)d_in[1];
  const int*   w1  = (const int*)d_in[2];
  const float* ws1 = (const float*)d_in[3];
  const int*   w2  = (const int*)d_in[4];
  const float* ws2 = (const float*)d_in[5];
  // d_in[6] = smooth_scales: unused by the reference
  const float* es  = (const float*)d_in[7];
  float* out = (float*)d_out;
  char* ws = (char*)d_ws;

  unsigned int*  counts   = (unsigned int*)(ws + OFF_CNT);
  unsigned int*  rowmax   = (unsigned int*)(ws + OFF_ROWMAX);
  unsigned short* xq      = (unsigned short*)(ws + OFF_XQ);
  float*         s0       = (float*)(ws + OFF_S0);
  float*         s1       = (float*)(ws + OFF_S1);
  int*           row_list = (int*)(ws + OFF_LIST);
  float*         act      = (float*)(ws + OFF_ACT);
  unsigned short* aq      = (unsigned short*)(ws + OFF_AQ);
  float*         y2       = (float*)(ws + OFF_Y2);

  hipMemsetAsync(ws, 0, 4096 + TK_ * 4, stream);  // counts + rowmax

  k_quant<<<T_, 256, 0, stream>>>(x, xq, s0);
  k_scatter<<<TK_ / 256, 256, 0, stream>>>(eid, counts, row_list);
  k_gemm1<<<dim3(16, E_), 512, 0, stream>>>(xq, w1, ws1, s0, counts, row_list, act, rowmax);
  k_requant<<<TK_, 256, 0, stream>>>(act, rowmax, aq, s1);
  k_gemm2<<<dim3(16, E_), 512, 0, stream>>>(aq, w2, ws2, s1, counts, row_list, y2);
  k_combine<<<(T_ * H_) / 256, 256, 0, stream>>>(y2, es, out);
}

// Round 2
// 180.595 us; speedup vs baseline: 1.3922x; 1.3922x over previous
//
#include <hip/hip_runtime.h>
#include <hip/hip_bf16.h>
#include <stdint.h>

#define E_   16
#define T_   512
#define KTOP 8
#define H_   2048
#define I_   1024
#define TK_  4096

typedef __attribute__((ext_vector_type(4))) int i32x4;

// ---- ws layout (bytes) ----
#define OFF_CNT     0                          // u32[16]
#define OFF_ROWMAX  4096                       // u32[4096]
#define OFF_XQ      32768                      // i8 [512][2048] = 1MB
#define OFF_S0      (OFF_XQ + T_*H_)           // f32[512]
#define OFF_S1      (OFF_S0 + 4096)            // f32[4096]
#define OFF_LIST    (OFF_S1 + TK_*4)           // i32[16][4096]
#define OFF_ACT     (OFF_LIST + E_*TK_*4)      // f32[4096][1024] = 16MB
#define OFF_AQ      (OFF_ACT + (size_t)TK_*I_*4)  // i8[4096][1024] = 4MB
#define OFF_Y2      (OFF_AQ + (size_t)TK_*I_)     // f32[4096][2048] = 32MB

__device__ __forceinline__ void g2l16(const void* g, void* l) {
  __builtin_amdgcn_global_load_lds(
      (const __attribute__((address_space(1))) void*)g,
      (__attribute__((address_space(3))) void*)l, 16, 0, 0);
}

// ---------------- dynamic quant of x -> int8 ----------------
__global__ void k_quant(const float* __restrict__ x, signed char* __restrict__ xq,
                        float* __restrict__ s0) {
  int t = blockIdx.x, tid = threadIdx.x;
  const float4* xr = (const float4*)(x + (size_t)t * H_);
  float4 a = xr[tid * 2 + 0], b = xr[tid * 2 + 1];
  float m = fmaxf(
      fmaxf(fmaxf(fabsf(a.x), fabsf(a.y)), fmaxf(fabsf(a.z), fabsf(a.w))),
      fmaxf(fmaxf(fabsf(b.x), fabsf(b.y)), fmaxf(fabsf(b.z), fabsf(b.w))));
  for (int o = 32; o > 0; o >>= 1) m = fmaxf(m, __shfl_xor(m, o));
  __shared__ float wm[4];
  if ((tid & 63) == 0) wm[tid >> 6] = m;
  __syncthreads();
  m = fmaxf(fmaxf(wm[0], wm[1]), fmaxf(wm[2], wm[3]));
  float s = m / 127.0f;
  if (!(s > 0.f)) s = 1.0f;
  if (tid == 0) s0[t] = s;
  float v[8] = {a.x, a.y, a.z, a.w, b.x, b.y, b.z, b.w};
  unsigned int lo = 0, hi = 0;
#pragma unroll
  for (int j = 0; j < 4; ++j) {
    float qf = fminf(fmaxf(rintf(v[j] / s), -128.f), 127.f);
    lo |= ((unsigned)((int)qf & 0xFF)) << (8 * j);
  }
#pragma unroll
  for (int j = 0; j < 4; ++j) {
    float qf = fminf(fmaxf(rintf(v[4 + j] / s), -128.f), 127.f);
    hi |= ((unsigned)((int)qf & 0xFF)) << (8 * j);
  }
  ((uint2*)(xq + (size_t)t * H_))[tid] = make_uint2(lo, hi);
}

// ---------------- expert dispatch ----------------
__global__ void k_scatter(const int* __restrict__ eids, unsigned int* __restrict__ counts,
                          int* __restrict__ row_list) {
  int i = blockIdx.x * blockDim.x + threadIdx.x;
  int e = eids[i];
  int pos = (int)atomicAdd(&counts[e], 1u);
  row_list[e * TK_ + pos] = i;
}

// ---------------- grouped GEMM kernels ----------------
#define BM_   320
#define ABUF  20480   // 20 mi-tiles * 1024B
#define BBUF  4096    // 4 kg * 64 cols * 16B

__launch_bounds__(256, 2)
__global__ void k_gemm1(const signed char* __restrict__ xq, const int* __restrict__ w1,
                        const float* __restrict__ ws1, const float* __restrict__ s0,
                        const unsigned int* __restrict__ counts,
                        const int* __restrict__ row_list,
                        float* __restrict__ act, unsigned int* __restrict__ rowmax) {
  __shared__ alignas(16) char smem[2 * ABUF + 2 * BBUF];
  int e = blockIdx.y;
  int cnt = (int)counts[e];
  if (cnt == 0) return;
  int p0 = blockIdx.x * 32;                       // 32 act cols per block
  const int* rl = row_list + e * TK_;
  const int* we = w1 + (size_t)e * H_ * (2 * I_);
  const float* wsc = ws1 + (size_t)e * (2 * I_);

  int tid = threadIdx.x, w = tid >> 6, lane = tid & 63;
  int l15 = lane & 15, l4 = lane >> 4;

  // B staging role: logical col bc (0..31 left, 32..63 right), k-group bkg
  int bc = tid & 63, bkg = tid >> 6;
  int bgcol = (bc < 32) ? (p0 + bc) : (I_ + p0 + (bc - 32));
  const int* bsrc0 = we + (size_t)(bkg * 16) * 2048 + bgcol;
  char* bw0 = smem + 2 * ABUF + bkg * 1024 + bc * 16;

  int nch = (cnt + BM_ - 1) / BM_;
  for (int ch = 0; ch < nch; ++ch) {
    int rbase = ch * BM_;
    const signed char* gA[5];
#pragma unroll
    for (int i = 0; i < 5; ++i) {
      int gr = rbase + w * 80 + i * 16 + l15;
      int tok = rl[gr < cnt ? gr : 0] >> 3;
      gA[i] = xq + (size_t)tok * H_ + l4 * 16;
    }
    i32x4 acc[5][4];
#pragma unroll
    for (int i = 0; i < 5; ++i)
#pragma unroll
      for (int n = 0; n < 4; ++n) acc[i][n] = (i32x4)(0);

    int breg[16];
    // prologue: stage k-tile 0 into buf 0
#pragma unroll
    for (int i = 0; i < 5; ++i) g2l16(gA[i], smem + (w * 5 + i) * 1024);
#pragma unroll
    for (int j = 0; j < 16; ++j) breg[j] = bsrc0[(size_t)j * 2048];
    {
      i32x4 pk;
#pragma unroll
      for (int d = 0; d < 4; ++d)
        pk[d] = (breg[4 * d] & 0xFF) | ((breg[4 * d + 1] & 0xFF) << 8) |
                ((breg[4 * d + 2] & 0xFF) << 16) | (breg[4 * d + 3] << 24);
      *(i32x4*)bw0 = pk;
    }
    __syncthreads();

    int buf = 0;
    for (int t = 0; t < H_ / 64; ++t) {
      bool more = (t + 1) < H_ / 64;
      if (more) {
        int k0n = (t + 1) * 64;
#pragma unroll
        for (int i = 0; i < 5; ++i)
          g2l16(gA[i] + k0n, smem + (buf ^ 1) * ABUF + (w * 5 + i) * 1024);
#pragma unroll
        for (int j = 0; j < 16; ++j) breg[j] = bsrc0[(size_t)(k0n + j) * 2048];
      }
      const char* Ab = smem + buf * ABUF;
      const char* Bb = smem + 2 * ABUF + buf * BBUF;
      i32x4 af[5], bf[4];
#pragma unroll
      for (int i = 0; i < 5; ++i)
        af[i] = *(const i32x4*)(Ab + (w * 5 + i) * 1024 + lane * 16);
#pragma unroll
      for (int n = 0; n < 4; ++n)
        bf[n] = *(const i32x4*)(Bb + l4 * 1024 + (n * 16 + l15) * 16);
#pragma unroll
      for (int i = 0; i < 5; ++i)
#pragma unroll
        for (int n = 0; n < 4; ++n)
          acc[i][n] = __builtin_amdgcn_mfma_i32_16x16x64_i8(af[i], bf[n], acc[i][n], 0, 0, 0);
      if (more) {
        i32x4 pk;
#pragma unroll
        for (int d = 0; d < 4; ++d)
          pk[d] = (breg[4 * d] & 0xFF) | ((breg[4 * d + 1] & 0xFF) << 8) |
                  ((breg[4 * d + 2] & 0xFF) << 16) | (breg[4 * d + 3] << 24);
        *(i32x4*)(bw0 + (buf ^ 1) * BBUF) = pk;
      }
      __syncthreads();
      buf ^= 1;
    }

    // epilogue: dequant + SwiGLU (left=acc[n], right=acc[n+2], same lane) + rowmax
#pragma unroll
    for (int mi = 0; mi < 5; ++mi) {
#pragma unroll
      for (int r = 0; r < 4; ++r) {
        int gr = rbase + w * 80 + mi * 16 + l4 * 4 + r;
        bool valid = gr < cnt;
        int irow = rl[valid ? gr : 0];
        float s0v = s0[irow >> 3];
        float rowm = 0.f, av0 = 0.f, av1 = 0.f;
#pragma unroll
        for (int n = 0; n < 2; ++n) {
          int colL = p0 + n * 16 + l15;
          float yl = (float)acc[mi][n][r] * wsc[colL] * s0v;
          float yr = (float)acc[mi][n + 2][r] * wsc[I_ + colL] * s0v;
          float actv = (yl / (1.f + expf(-yl))) * yr;
          if (n == 0) av0 = actv; else av1 = actv;
          rowm = fmaxf(rowm, fabsf(actv));
        }
        rowm = fmaxf(rowm, __shfl_xor(rowm, 1));
        rowm = fmaxf(rowm, __shfl_xor(rowm, 2));
        rowm = fmaxf(rowm, __shfl_xor(rowm, 4));
        rowm = fmaxf(rowm, __shfl_xor(rowm, 8));
        if (valid) {
          act[(size_t)irow * I_ + p0 + l15] = av0;
          act[(size_t)irow * I_ + p0 + 16 + l15] = av1;
          if (l15 == 0) atomicMax(rowmax + irow, __float_as_uint(rowm));
        }
      }
    }
  }
}

// ---------------- requant act -> int8 + s1 ----------------
__global__ void k_requant(const float* __restrict__ act, const unsigned int* __restrict__ rowmax,
                          signed char* __restrict__ aq, float* __restrict__ s1) {
  int i = blockIdx.x, tid = threadIdx.x;
  float m = __uint_as_float(rowmax[i]);
  float s = (m > 0.f) ? (m / 127.0f) : 1.0f;
  if (tid == 0) s1[i] = s;
  float4 v = ((const float4*)(act + (size_t)i * I_))[tid];
  float vv[4] = {v.x, v.y, v.z, v.w};
  unsigned int pk = 0;
#pragma unroll
  for (int j = 0; j < 4; ++j) {
    float qf = fminf(fmaxf(rintf(vv[j] / s), -128.f), 127.f);
    pk |= ((unsigned)((int)qf & 0xFF)) << (8 * j);
  }
  ((unsigned int*)(aq + (size_t)i * I_))[tid] = pk;
}

// ---------------- grouped GEMM2 + dequant ----------------
__launch_bounds__(256, 2)
__global__ void k_gemm2(const signed char* __restrict__ aq, const int* __restrict__ w2,
                        const float* __restrict__ ws2, const float* __restrict__ s1,
                        const unsigned int* __restrict__ counts,
                        const int* __restrict__ row_list,
                        float* __restrict__ y2) {
  __shared__ alignas(16) char smem[2 * ABUF + 2 * BBUF];
  int e = blockIdx.y;
  int cnt = (int)counts[e];
  if (cnt == 0) return;
  int n0 = blockIdx.x * 64;
  const int* rl = row_list + e * TK_;
  const int* we = w2 + (size_t)e * I_ * H_;
  const float* wsc = ws2 + (size_t)e * H_;

  int tid = threadIdx.x, w = tid >> 6, lane = tid & 63;
  int l15 = lane & 15, l4 = lane >> 4;

  int bc = tid & 63, bkg = tid >> 6;
  const int* bsrc0 = we + (size_t)(bkg * 16) * H_ + n0 + bc;
  char* bw0 = smem + 2 * ABUF + bkg * 1024 + bc * 16;

  int nch = (cnt + BM_ - 1) / BM_;
  for (int ch = 0; ch < nch; ++ch) {
    int rbase = ch * BM_;
    const signed char* gA[5];
#pragma unroll
    for (int i = 0; i < 5; ++i) {
      int gr = rbase + w * 80 + i * 16 + l15;
      gA[i] = aq + (size_t)rl[gr < cnt ? gr : 0] * I_ + l4 * 16;
    }
    i32x4 acc[5][4];
#pragma unroll
    for (int i = 0; i < 5; ++i)
#pragma unroll
      for (int n = 0; n < 4; ++n) acc[i][n] = (i32x4)(0);

    int breg[16];
#pragma unroll
    for (int i = 0; i < 5; ++i) g2l16(gA[i], smem + (w * 5 + i) * 1024);
#pragma unroll
    for (int j = 0; j < 16; ++j) breg[j] = bsrc0[(size_t)j * H_];
    {
      i32x4 pk;
#pragma unroll
      for (int d = 0; d < 4; ++d)
        pk[d] = (breg[4 * d] & 0xFF) | ((breg[4 * d + 1] & 0xFF) << 8) |
                ((breg[4 * d + 2] & 0xFF) << 16) | (breg[4 * d + 3] << 24);
      *(i32x4*)bw0 = pk;
    }
    __syncthreads();

    int buf = 0;
    for (int t = 0; t < I_ / 64; ++t) {
      bool more = (t + 1) < I_ / 64;
      if (more) {
        int k0n = (t + 1) * 64;
#pragma unroll
        for (int i = 0; i < 5; ++i)
          g2l16(gA[i] + k0n, smem + (buf ^ 1) * ABUF + (w * 5 + i) * 1024);
#pragma unroll
        for (int j = 0; j < 16; ++j) breg[j] = bsrc0[(size_t)(k0n + j) * H_];
      }
      const char* Ab = smem + buf * ABUF;
      const char* Bb = smem + 2 * ABUF + buf * BBUF;
      i32x4 af[5], bf[4];
#pragma unroll
      for (int i = 0; i < 5; ++i)
        af[i] = *(const i32x4*)(Ab + (w * 5 + i) * 1024 + lane * 16);
#pragma unroll
      for (int n = 0; n < 4; ++n)
        bf[n] = *(const i32x4*)(Bb + l4 * 1024 + (n * 16 + l15) * 16);
#pragma unroll
      for (int i = 0; i < 5; ++i)
#pragma unroll
        for (int n = 0; n < 4; ++n)
          acc[i][n] = __builtin_amdgcn_mfma_i32_16x16x64_i8(af[i], bf[n], acc[i][n], 0, 0, 0);
      if (more) {
        i32x4 pk;
#pragma unroll
        for (int d = 0; d < 4; ++d)
          pk[d] = (breg[4 * d] & 0xFF) | ((breg[4 * d + 1] & 0xFF) << 8) |
                  ((breg[4 * d + 2] & 0xFF) << 16) | (breg[4 * d + 3] << 24);
        *(i32x4*)(bw0 + (buf ^ 1) * BBUF) = pk;
      }
      __syncthreads();
      buf ^= 1;
    }

#pragma unroll
    for (int mi = 0; mi < 5; ++mi) {
#pragma unroll
      for (int r = 0; r < 4; ++r) {
        int gr = rbase + w * 80 + mi * 16 + l4 * 4 + r;
        if (gr < cnt) {
          int irow = rl[gr];
          float s1v = s1[irow];
#pragma unroll
          for (int n = 0; n < 4; ++n) {
            int col = n0 + n * 16 + l15;
            y2[(size_t)irow * H_ + col] = (float)acc[mi][n][r] * wsc[col] * s1v;
          }
        }
      }
    }
  }
}

// ---------------- combine ----------------
__global__ void k_combine(const float* __restrict__ y2, const float* __restrict__ es,
                          float* __restrict__ out) {
  int idx = blockIdx.x * 256 + threadIdx.x;
  int t = idx >> 11;
  const float* esr = es + (size_t)t * KTOP;
  float s = 0.f;
#pragma unroll
  for (int k = 0; k < KTOP; ++k)
    s += esr[k] * y2[(size_t)(t * KTOP + k) * H_ + (idx & (H_ - 1))];
  out[idx] = s;
}

extern "C" void kernel_launch(void* const* d_in, const int* in_sizes, int n_in,
                              void* d_out, int out_size, void* d_ws, size_t ws_size,
                              hipStream_t stream) {
  const float* x   = (const float*)d_in[0];
  const int*   eid = (const int*)d_in[1];
  const int*   w1  = (const int*)d_in[2];
  const float* ws1 = (const float*)d_in[3];
  const int*   w2  = (const int*)d_in[4];
  const float* ws2 = (const float*)d_in[5];
  const float* es  = (const float*)d_in[7];
  float* out = (float*)d_out;
  char* ws = (char*)d_ws;

  unsigned int*  counts   = (unsigned int*)(ws + OFF_CNT);
  unsigned int*  rowmax   = (unsigned int*)(ws + OFF_ROWMAX);
  signed char*   xq       = (signed char*)(ws + OFF_XQ);
  float*         s0       = (float*)(ws + OFF_S0);
  float*         s1       = (float*)(ws + OFF_S1);
  int*           row_list = (int*)(ws + OFF_LIST);
  float*         act      = (float*)(ws + OFF_ACT);
  signed char*   aq       = (signed char*)(ws + OFF_AQ);
  float*         y2       = (float*)(ws + OFF_Y2);

  hipMemsetAsync(ws, 0, 4096 + TK_ * 4, stream);  // counts + rowmax

  k_quant<<<T_, 256, 0, stream>>>(x, xq, s0);
  k_scatter<<<TK_ / 256, 256, 0, stream>>>(eid, counts, row_list);
  k_gemm1<<<dim3(32, E_), 256, 0, stream>>>(xq, w1, ws1, s0, counts, row_list, act, rowmax);
  k_requant<<<TK_, 256, 0, stream>>>(act, rowmax, aq, s1);
  k_gemm2<<<dim3(32, E_), 256, 0, stream>>>(aq, w2, ws2, s1, counts, row_list, y2);
  k_combine<<<(T_ * H_) / 256, 256, 0, stream>>>(y2, es, out);
}

// Round 3
// 178.204 us; speedup vs baseline: 1.4108x; 1.0134x over previous
//
#include <hip/hip_runtime.h>
#include <hip/hip_bf16.h>
#include <stdint.h>

#define E_   16
#define T_   512
#define KTOP 8
#define H_   2048
#define I_   1024
#define TK_  4096

typedef __attribute__((ext_vector_type(4))) int i32x4;

// ---- ws layout (bytes) ----
#define OFF_CNT     0                          // u32[16]
#define OFF_ROWMAX  4096                       // u32[4096]
#define OFF_XQ      32768                      // i8 [512][2048] = 1MB
#define OFF_S0      (OFF_XQ + T_*H_)           // f32[512]
#define OFF_S1      (OFF_S0 + 4096)            // f32[4096]
#define OFF_LIST    (OFF_S1 + TK_*4)           // i32[16][4096]
#define OFF_ACT     (OFF_LIST + E_*TK_*4)      // f32[4096][1024] = 16MB
#define OFF_AQ      (OFF_ACT + (size_t)TK_*I_*4)  // i8[4096][1024] = 4MB
#define OFF_Y2      (OFF_AQ + (size_t)TK_*I_)     // bf16[4096][2048] = 16MB

__device__ __forceinline__ void g2l16(const void* g, void* l) {
  __builtin_amdgcn_global_load_lds(
      (const __attribute__((address_space(1))) void*)g,
      (__attribute__((address_space(3))) void*)l, 16, 0, 0);
}

#define SCHEDB() __builtin_amdgcn_sched_barrier(0)
#define VMCNT16() asm volatile("s_waitcnt vmcnt(16)" ::: "memory")
#define VMCNT0()  asm volatile("s_waitcnt vmcnt(0)" ::: "memory")
#define LGKM0()   asm volatile("s_waitcnt lgkmcnt(0)" ::: "memory")
#define BAR()     __builtin_amdgcn_s_barrier()

// ---------------- zero counts + rowmax ----------------
__global__ void k_zero(unsigned int* __restrict__ p) {
  int i = blockIdx.x * 256 + threadIdx.x;
  if (i < 5120) p[i] = 0;   // covers counts(16) + gap + rowmax(4096)
}

// ---------------- dynamic quant of x -> int8 (+ fused scatter) ----------------
__global__ void k_quant(const float* __restrict__ x, signed char* __restrict__ xq,
                        float* __restrict__ s0, const int* __restrict__ eids,
                        unsigned int* __restrict__ counts, int* __restrict__ row_list) {
  int t = blockIdx.x, tid = threadIdx.x;
  if (tid < KTOP) {
    int e = eids[t * KTOP + tid];
    int pos = (int)atomicAdd(&counts[e], 1u);
    row_list[e * TK_ + pos] = t * KTOP + tid;
  }
  const float4* xr = (const float4*)(x + (size_t)t * H_);
  float4 a = xr[tid * 2 + 0], b = xr[tid * 2 + 1];
  float m = fmaxf(
      fmaxf(fmaxf(fabsf(a.x), fabsf(a.y)), fmaxf(fabsf(a.z), fabsf(a.w))),
      fmaxf(fmaxf(fabsf(b.x), fabsf(b.y)), fmaxf(fabsf(b.z), fabsf(b.w))));
  for (int o = 32; o > 0; o >>= 1) m = fmaxf(m, __shfl_xor(m, o));
  __shared__ float wm[4];
  if ((tid & 63) == 0) wm[tid >> 6] = m;
  __syncthreads();
  m = fmaxf(fmaxf(wm[0], wm[1]), fmaxf(wm[2], wm[3]));
  float s = m / 127.0f;
  if (!(s > 0.f)) s = 1.0f;
  if (tid == 0) s0[t] = s;
  float v[8] = {a.x, a.y, a.z, a.w, b.x, b.y, b.z, b.w};
  unsigned int lo = 0, hi = 0;
#pragma unroll
  for (int j = 0; j < 4; ++j) {
    float qf = fminf(fmaxf(rintf(v[j] / s), -128.f), 127.f);
    lo |= ((unsigned)((int)qf & 0xFF)) << (8 * j);
  }
#pragma unroll
  for (int j = 0; j < 4; ++j) {
    float qf = fminf(fmaxf(rintf(v[4 + j] / s), -128.f), 127.f);
    hi |= ((unsigned)((int)qf & 0xFF)) << (8 * j);
  }
  ((uint2*)(xq + (size_t)t * H_))[tid] = make_uint2(lo, hi);
}

// ---------------- grouped GEMM common bits ----------------
#define BM_   320
#define ABUF  20480   // 20 mi-tiles * 1024B
#define BBUF  4096    // 4 kg * 64 cols * 16B
#define WSTR  2048    // B k-row stride in ints (both gemms)

#define PACKW(SRC, DST) do {                                              \
    i32x4 pk_;                                                            \
    _Pragma("unroll")                                                     \
    for (int d_ = 0; d_ < 4; ++d_)                                        \
      pk_[d_] = ((SRC)[4*d_] & 0xFF) | (((SRC)[4*d_+1] & 0xFF) << 8) |    \
                (((SRC)[4*d_+2] & 0xFF) << 16) | ((SRC)[4*d_+3] << 24);   \
    *(i32x4*)(DST) = pk_;                                                 \
  } while (0)

// One k-tile: issue A(t+1) g2l (unless LAST), issue B(t+2) into IS bank,
// MFMA from buf RD, then (unless LAST) vmcnt(16) + pack PK bank + barrier.
#define TILE_BODY(TT, RD, PK, IS, LAST, NT) do {                          \
    if (!(LAST)) {                                                        \
      _Pragma("unroll")                                                   \
      for (int i_ = 0; i_ < 5; ++i_)                                      \
        g2l16(gA[i_] + ((TT) + 1) * 64,                                   \
              smem + ((RD) ^ 1) * ABUF + (w * 5 + i_) * 1024);            \
    }                                                                     \
    SCHEDB();                                                             \
    {                                                                     \
      int kk_ = (TT) + 2; if (kk_ > (NT) - 1) kk_ = (NT) - 1;             \
      _Pragma("unroll")                                                   \
      for (int j_ = 0; j_ < 16; ++j_)                                     \
        (IS)[j_] = bsrc[(size_t)(kk_ * 64 + j_) * WSTR];                  \
    }                                                                     \
    SCHEDB();                                                             \
    {                                                                     \
      const char* Ab_ = smem + (RD) * ABUF;                               \
      const char* Bb_ = smem + 2 * ABUF + (RD) * BBUF;                    \
      i32x4 af_[5], bf_[4];                                               \
      _Pragma("unroll")                                                   \
      for (int i_ = 0; i_ < 5; ++i_)                                      \
        af_[i_] = *(const i32x4*)(Ab_ + (w * 5 + i_) * 1024 + lane * 16); \
      _Pragma("unroll")                                                   \
      for (int n_ = 0; n_ < 4; ++n_)                                      \
        bf_[n_] = *(const i32x4*)(Bb_ + l4 * 1024 + (n_ * 16 + l15) * 16);\
      _Pragma("unroll")                                                   \
      for (int i_ = 0; i_ < 5; ++i_)                                      \
        _Pragma("unroll")                                                 \
        for (int n_ = 0; n_ < 4; ++n_)                                    \
          acc[i_][n_] = __builtin_amdgcn_mfma_i32_16x16x64_i8(            \
              af_[i_], bf_[n_], acc[i_][n_], 0, 0, 0);                    \
    }                                                                     \
    if (!(LAST)) {                                                        \
      VMCNT16(); SCHEDB();                                                \
      PACKW(PK, bdst0 + (((RD) ^ 1)) * BBUF);                             \
      LGKM0(); BAR(); SCHEDB();                                           \
    }                                                                     \
  } while (0)

// ---------------- grouped GEMM1 + SwiGLU + rowmax ----------------
__launch_bounds__(256, 2)
__global__ void k_gemm1(const signed char* __restrict__ xq, const int* __restrict__ w1,
                        const float* __restrict__ ws1, const float* __restrict__ s0,
                        const unsigned int* __restrict__ counts,
                        const int* __restrict__ row_list,
                        float* __restrict__ act, unsigned int* __restrict__ rowmax) {
  __shared__ alignas(16) char smem[2 * ABUF + 2 * BBUF];
  int e = blockIdx.y;
  int cnt = (int)counts[e];
  if (cnt == 0) return;
  int p0 = blockIdx.x * 32;
  const int* rl = row_list + e * TK_;
  const int* we = w1 + (size_t)e * H_ * (2 * I_);
  const float* wsc = ws1 + (size_t)e * (2 * I_);

  int tid = threadIdx.x, w = tid >> 6, lane = tid & 63;
  int l15 = lane & 15, l4 = lane >> 4;
  int bc = tid & 63, bkg = tid >> 6;
  int bgcol = (bc < 32) ? (p0 + bc) : (I_ + p0 + (bc - 32));
  const int* bsrc = we + (size_t)(bkg * 16) * WSTR + bgcol;
  char* bdst0 = smem + 2 * ABUF + bkg * 1024 + bc * 16;

  const int NT = H_ / 64;
  int nch = (cnt + BM_ - 1) / BM_;
  for (int ch = 0; ch < nch; ++ch) {
    int rbase = ch * BM_;
    const signed char* gA[5];
#pragma unroll
    for (int i = 0; i < 5; ++i) {
      int gr = rbase + w * 80 + i * 16 + l15;
      int tok = rl[gr < cnt ? gr : 0] >> 3;
      gA[i] = xq + (size_t)tok * H_ + l4 * 16;
    }
    i32x4 acc[5][4];
#pragma unroll
    for (int i = 0; i < 5; ++i)
#pragma unroll
      for (int n = 0; n < 4; ++n) acc[i][n] = (i32x4)(0);

    int brA[16], brB[16];
    // prologue: A(0) g2l, B(0)->brA, B(1)->brB, wait(16), pack B(0), barrier
    SCHEDB();
#pragma unroll
    for (int i = 0; i < 5; ++i) g2l16(gA[i], smem + (w * 5 + i) * 1024);
    SCHEDB();
#pragma unroll
    for (int j = 0; j < 16; ++j) brA[j] = bsrc[(size_t)j * WSTR];
    SCHEDB();
#pragma unroll
    for (int j = 0; j < 16; ++j) brB[j] = bsrc[(size_t)(64 + j) * WSTR];
    SCHEDB();
    VMCNT16(); SCHEDB();
    PACKW(brA, bdst0);
    LGKM0(); BAR(); SCHEDB();

    for (int t = 0; t < NT; t += 2) {
      TILE_BODY(t,     0, brB, brA, false,          NT);
      TILE_BODY(t + 1, 1, brA, brB, (t + 2 == NT),  NT);
    }

    // epilogue: dequant + SwiGLU + rowmax
#pragma unroll
    for (int mi = 0; mi < 5; ++mi) {
#pragma unroll
      for (int r = 0; r < 4; ++r) {
        int gr = rbase + w * 80 + mi * 16 + l4 * 4 + r;
        bool valid = gr < cnt;
        int irow = rl[valid ? gr : 0];
        float s0v = s0[irow >> 3];
        float rowm = 0.f, av0 = 0.f, av1 = 0.f;
#pragma unroll
        for (int n = 0; n < 2; ++n) {
          int colL = p0 + n * 16 + l15;
          float yl = (float)acc[mi][n][r] * wsc[colL] * s0v;
          float yr = (float)acc[mi][n + 2][r] * wsc[I_ + colL] * s0v;
          float actv = (yl / (1.f + expf(-yl))) * yr;
          if (n == 0) av0 = actv; else av1 = actv;
          rowm = fmaxf(rowm, fabsf(actv));
        }
        rowm = fmaxf(rowm, __shfl_xor(rowm, 1));
        rowm = fmaxf(rowm, __shfl_xor(rowm, 2));
        rowm = fmaxf(rowm, __shfl_xor(rowm, 4));
        rowm = fmaxf(rowm, __shfl_xor(rowm, 8));
        if (valid) {
          act[(size_t)irow * I_ + p0 + l15] = av0;
          act[(size_t)irow * I_ + p0 + 16 + l15] = av1;
          if (l15 == 0) atomicMax(rowmax + irow, __float_as_uint(rowm));
        }
      }
    }
  }
}

// ---------------- requant act -> int8 + s1 ----------------
__global__ void k_requant(const float* __restrict__ act, const unsigned int* __restrict__ rowmax,
                          signed char* __restrict__ aq, float* __restrict__ s1) {
  int i = blockIdx.x, tid = threadIdx.x;
  float m = __uint_as_float(rowmax[i]);
  float s = (m > 0.f) ? (m / 127.0f) : 1.0f;
  if (tid == 0) s1[i] = s;
  float4 v = ((const float4*)(act + (size_t)i * I_))[tid];
  float vv[4] = {v.x, v.y, v.z, v.w};
  unsigned int pk = 0;
#pragma unroll
  for (int j = 0; j < 4; ++j) {
    float qf = fminf(fmaxf(rintf(vv[j] / s), -128.f), 127.f);
    pk |= ((unsigned)((int)qf & 0xFF)) << (8 * j);
  }
  ((unsigned int*)(aq + (size_t)i * I_))[tid] = pk;
}

// ---------------- grouped GEMM2 + dequant + es fold -> bf16 ----------------
__launch_bounds__(256, 2)
__global__ void k_gemm2(const signed char* __restrict__ aq, const int* __restrict__ w2,
                        const float* __restrict__ ws2, const float* __restrict__ s1,
                        const float* __restrict__ es,
                        const unsigned int* __restrict__ counts,
                        const int* __restrict__ row_list,
                        __hip_bfloat16* __restrict__ y2h) {
  __shared__ alignas(16) char smem[2 * ABUF + 2 * BBUF];
  int e = blockIdx.y;
  int cnt = (int)counts[e];
  if (cnt == 0) return;
  int n0 = blockIdx.x * 64;
  const int* rl = row_list + e * TK_;
  const int* we = w2 + (size_t)e * I_ * H_;
  const float* wsc = ws2 + (size_t)e * H_;

  int tid = threadIdx.x, w = tid >> 6, lane = tid & 63;
  int l15 = lane & 15, l4 = lane >> 4;
  int bc = tid & 63, bkg = tid >> 6;
  const int* bsrc = we + (size_t)(bkg * 16) * WSTR + n0 + bc;
  char* bdst0 = smem + 2 * ABUF + bkg * 1024 + bc * 16;

  const int NT = I_ / 64;
  int nch = (cnt + BM_ - 1) / BM_;
  for (int ch = 0; ch < nch; ++ch) {
    int rbase = ch * BM_;
    const signed char* gA[5];
#pragma unroll
    for (int i = 0; i < 5; ++i) {
      int gr = rbase + w * 80 + i * 16 + l15;
      gA[i] = aq + (size_t)rl[gr < cnt ? gr : 0] * I_ + l4 * 16;
    }
    i32x4 acc[5][4];
#pragma unroll
    for (int i = 0; i < 5; ++i)
#pragma unroll
      for (int n = 0; n < 4; ++n) acc[i][n] = (i32x4)(0);

    int brA[16], brB[16];
    SCHEDB();
#pragma unroll
    for (int i = 0; i < 5; ++i) g2l16(gA[i], smem + (w * 5 + i) * 1024);
    SCHEDB();
#pragma unroll
    for (int j = 0; j < 16; ++j) brA[j] = bsrc[(size_t)j * WSTR];
    SCHEDB();
#pragma unroll
    for (int j = 0; j < 16; ++j) brB[j] = bsrc[(size_t)(64 + j) * WSTR];
    SCHEDB();
    VMCNT16(); SCHEDB();
    PACKW(brA, bdst0);
    LGKM0(); BAR(); SCHEDB();

    for (int t = 0; t < NT; t += 2) {
      TILE_BODY(t,     0, brB, brA, false,          NT);
      TILE_BODY(t + 1, 1, brA, brB, (t + 2 == NT),  NT);
    }

#pragma unroll
    for (int mi = 0; mi < 5; ++mi) {
#pragma unroll
      for (int r = 0; r < 4; ++r) {
        int gr = rbase + w * 80 + mi * 16 + l4 * 4 + r;
        if (gr < cnt) {
          int irow = rl[gr];
          float sc = s1[irow] * es[irow];
#pragma unroll
          for (int n = 0; n < 4; ++n) {
            int col = n0 + n * 16 + l15;
            float v = (float)acc[mi][n][r] * wsc[col] * sc;
            y2h[(size_t)irow * H_ + col] = __float2bfloat16(v);
          }
        }
      }
    }
  }
}

// ---------------- combine (es already folded) ----------------
__global__ void k_combine(const __hip_bfloat16* __restrict__ y2h, float* __restrict__ out) {
  int idx = blockIdx.x * 256 + threadIdx.x;   // each handles 8 h
  int t = idx >> 8;
  int h0 = (idx & 255) * 8;
  float s[8];
#pragma unroll
  for (int j = 0; j < 8; ++j) s[j] = 0.f;
#pragma unroll
  for (int k = 0; k < KTOP; ++k) {
    const __hip_bfloat16* p = y2h + ((size_t)(t * KTOP + k) * H_ + h0);
    uint4 u = *(const uint4*)p;
    const __hip_bfloat16* b = (const __hip_bfloat16*)&u;
#pragma unroll
    for (int j = 0; j < 8; ++j) s[j] += __bfloat162float(b[j]);
  }
  float4 o0 = make_float4(s[0], s[1], s[2], s[3]);
  float4 o1 = make_float4(s[4], s[5], s[6], s[7]);
  float4* dst = (float4*)(out + (size_t)t * H_ + h0);
  dst[0] = o0; dst[1] = o1;
}

extern "C" void kernel_launch(void* const* d_in, const int* in_sizes, int n_in,
                              void* d_out, int out_size, void* d_ws, size_t ws_size,
                              hipStream_t stream) {
  const float* x   = (const float*)d_in[0];
  const int*   eid = (const int*)d_in[1];
  const int*   w1  = (const int*)d_in[2];
  const float* ws1 = (const float*)d_in[3];
  const int*   w2  = (const int*)d_in[4];
  const float* ws2 = (const float*)d_in[5];
  const float* es  = (const float*)d_in[7];
  float* out = (float*)d_out;
  char* ws = (char*)d_ws;

  unsigned int*  counts   = (unsigned int*)(ws + OFF_CNT);
  unsigned int*  rowmax   = (unsigned int*)(ws + OFF_ROWMAX);
  signed char*   xq       = (signed char*)(ws + OFF_XQ);
  float*         s0       = (float*)(ws + OFF_S0);
  float*         s1       = (float*)(ws + OFF_S1);
  int*           row_list = (int*)(ws + OFF_LIST);
  float*         act      = (float*)(ws + OFF_ACT);
  signed char*   aq       = (signed char*)(ws + OFF_AQ);
  __hip_bfloat16* y2h     = (__hip_bfloat16*)(ws + OFF_Y2);

  k_zero<<<20, 256, 0, stream>>>((unsigned int*)ws);
  k_quant<<<T_, 256, 0, stream>>>(x, xq, s0, eid, counts, row_list);
  k_gemm1<<<dim3(32, E_), 256, 0, stream>>>(xq, w1, ws1, s0, counts, row_list, act, rowmax);
  k_requant<<<TK_, 256, 0, stream>>>(act, rowmax, aq, s1);
  k_gemm2<<<dim3(32, E_), 256, 0, stream>>>(aq, w2, ws2, s1, es, counts, row_list, y2h);
  k_combine<<<(T_ * H_ / 8) / 256, 256, 0, stream>>>(y2h, out);
}